// Round 5
// baseline (210.364 us; speedup 1.0000x reference)
//
#include <hip/hip_runtime.h>

#define BN_EPS 1e-5f

// Single fused kernel, one block per batch (grid=16, 1024 threads).
// Dependency cone of the only consumed output position:
//   out(8,8,8) <- x2[15..17]^3 (64ch) <- x1[29..35]^3 (32ch) <- voxel[28..36]^3
// All interior (no padding logic).
//
// __launch_bounds__(1024, 4): 4 waves/EU -> 1 block/CU -> VGPR cap 128.
// R4 lesson: default cap for 1024-thread blocks is 64 VGPRs -> wr2[27]+row+p2
// spilled to scratch (24 MB WRITE_SIZE, 15 ms dispatch). Peak live here ~105.
//
// Layouts (transaction-audited):
//   s_x1 channel-last [343 pos][32 ci]: conv2 does ds_read_b64 at pos*32+2j
//        -> banks {2j,2j+1} bijective over the 16-lane group, identical addrs
//        across the wave's 4 co-groups (broadcast). conv1 writes coalesced.
//   w2   4-chunk coalesced float4 bounce via 55 KB LDS (16 co per chunk),
//        synchronous staging (no prefetch regs), then per-lane LDS->reg.
//   conv2 row-register cache: 7 x float2 per (z,y) row, accumulators p2[9]
//        grouped by output-z so only ~105 hot VGPRs.
__global__ __launch_bounds__(1024, 4) void backbone_fused_kernel(
    const float* __restrict__ voxel,
    const float* __restrict__ w1, const float* __restrict__ g1,
    const float* __restrict__ b1, const float* __restrict__ m1, const float* __restrict__ v1,
    const float* __restrict__ w2, const float* __restrict__ g2,
    const float* __restrict__ b2, const float* __restrict__ m2, const float* __restrict__ v2,
    const float* __restrict__ w3, const float* __restrict__ g3,
    const float* __restrict__ b3, const float* __restrict__ m3, const float* __restrict__ v3,
    const float* __restrict__ wp, const float* __restrict__ bp,
    float* __restrict__ out)
{
    const int b   = blockIdx.x;
    const int tid = threadIdx.x;

    __shared__ __align__(16) float s_in[729];     // 9^3 input patch
    __shared__ float s_w1[864];                   // 32 x 27
    __shared__ __align__(16) float s_x1[10976];   // [343][32] channel-last
    __shared__ __align__(16) float s_wb[13824];   // w2 chunk: [16co][32ci][27]
    __shared__ __align__(16) float s_x2[1728];    // [64 co][27]
    __shared__ float s_x3[128];
    __shared__ __align__(16) float s_fc[1024];
    __shared__ float sa1[32], ss1[32];
    __shared__ float sa2[64], ss2[64];
    __shared__ float sa3[128], ss3[128];

    // ---- Phase 0: stage input patch + conv1 weights + folded BN consts ----
    const float* vb = voxel + (size_t)b * 262144;
    if (tid < 729) {
        int z = tid / 81, r = tid % 81, y = r / 9, x = r % 9;
        s_in[tid] = vb[(28 + z) * 4096 + (28 + y) * 64 + (28 + x)];
    }
    if (tid < 864) s_w1[tid] = w1[tid];
    if (tid >= 896) {                       // 128 ch of stage 3
        int c = tid - 896;
        float a = g3[c] * rsqrtf(v3[c] + BN_EPS);
        sa3[c] = a; ss3[c] = b3[c] - m3[c] * a;
    } else if (tid >= 832) {                // 64 ch of stage 2
        int c = tid - 832;
        float a = g2[c] * rsqrtf(v2[c] + BN_EPS);
        sa2[c] = a; ss2[c] = b2[c] - m2[c] * a;
    } else if (tid >= 800) {                // 32 ch of stage 1
        int c = tid - 800;
        float a = g1[c] * rsqrtf(v1[c] + BN_EPS);
        sa1[c] = a; ss1[c] = b1[c] - m1[c] * a;
    }
    __syncthreads();

    // ---- Phase 1: conv1 (stride 1) + BN + ReLU -> s_x1[pos][co] ----
    {
        const int co = tid & 31;            // constant across iterations
        float wc[27];
        #pragma unroll
        for (int k = 0; k < 27; ++k) wc[k] = s_w1[co * 27 + k];
        const float a = sa1[co], sh = ss1[co];
        for (int it = 0; it < 11; ++it) {
            int t = it * 1024 + tid;
            if (t < 10976) {
                int r = t >> 5;             // position 0..342
                int z = r / 49, rem = r % 49, y = rem / 7, x = rem % 7;
                float acc = 0.f;
                #pragma unroll
                for (int kd = 0; kd < 3; ++kd)
                #pragma unroll
                for (int kh = 0; kh < 3; ++kh)
                #pragma unroll
                for (int kw = 0; kw < 3; ++kw)
                    acc += s_in[(z + kd) * 81 + (y + kh) * 9 + (x + kw)]
                         * wc[kd * 9 + kh * 3 + kw];
                s_x1[t] = fmaxf(acc * a + sh, 0.f);   // t = pos*32 + co
            }
        }
    }

    // ---- Phase 1.5: w2 chunk bounce -> per-lane weight regs wr2[27] ----
    const int co = tid >> 4;        // 0..63 conv2 output channel
    const int j  = tid & 15;        // ci-pair index (ci = 2j, 2j+1)
    const int myck = co >> 4;       // which chunk holds my weights
    const float4* w2v = (const float4*)w2;
    float4* wbv = (float4*)s_wb;
    float2 wr2[27];
    #pragma unroll
    for (int c = 0; c < 4; ++c) {
        __syncthreads();            // prev chunk's readers done (c=0: conv1)
        for (int i = tid; i < 3456; i += 1024)      // coalesced float4 stage
            wbv[i] = w2v[c * 3456 + i];
        __syncthreads();
        if (myck == c) {
            const float* wb = s_wb + ((co & 15) * 32 + 2 * j) * 27;
            #pragma unroll
            for (int k = 0; k < 27; ++k) {
                wr2[k].x = wb[k];        // ci = 2j
                wr2[k].y = wb[27 + k];   // ci = 2j+1
            }
        }
    }

    // ---- Phase 2: conv2 (stride 2) + BN + ReLU -> s_x2[co][27] ----
    {
        const float a2 = sa2[co], sh2 = ss2[co];
        #pragma unroll
        for (int i = 0; i < 3; ++i) {       // output z-position group
            float2 p2[9];
            #pragma unroll
            for (int q = 0; q < 9; ++q) { p2[q].x = 0.f; p2[q].y = 0.f; }
            #pragma unroll
            for (int kd = 0; kd < 3; ++kd) {
                const int z = 2 * i + kd;   // x1 z-plane
                #pragma unroll
                for (int y = 0; y < 7; ++y) {
                    float2 row[7];          // x-row cache for (z,y)
                    #pragma unroll
                    for (int x = 0; x < 7; ++x)
                        row[x] = *(const float2*)&s_x1[((z * 7 + y) * 7 + x) * 32 + 2 * j];
                    #pragma unroll
                    for (int jj = 0; jj < 3; ++jj) {
                        const int kh = y - 2 * jj;
                        if (kh >= 0 && kh < 3) {
                            #pragma unroll
                            for (int k = 0; k < 3; ++k)
                            #pragma unroll
                            for (int kw = 0; kw < 3; ++kw) {
                                const float2 w = wr2[kd * 9 + kh * 3 + kw];
                                const float2 xv = row[2 * k + kw];
                                p2[jj * 3 + k].x += xv.x * w.x;
                                p2[jj * 3 + k].y += xv.y * w.y;
                            }
                        }
                    }
                }
            }
            #pragma unroll
            for (int q = 0; q < 9; ++q) {
                float s = p2[q].x + p2[q].y;
                s += __shfl_xor(s, 1);
                s += __shfl_xor(s, 2);
                s += __shfl_xor(s, 4);
                s += __shfl_xor(s, 8);
                if (j == 0)
                    s_x2[co * 27 + i * 9 + q] = fmaxf(s * a2 + sh2, 0.f);
            }
        }
    }
    __syncthreads();

    // ---- Phase 3: conv3 center + BN + ReLU -> s_x3[128] ----
    {
        const float4* xv4 = (const float4*)s_x2;   // 432 float4
        #pragma unroll
        for (int cc = 0; cc < 2; ++cc) {
            const int co3 = co + 64 * cc;          // co = tid>>4 reused
            const float4* wv = (const float4*)(w3 + (size_t)co3 * 1728);
            float acc = 0.f;
            #pragma unroll
            for (int t = 0; t < 27; ++t) {
                float4 w4 = wv[j + 16 * t];
                float4 x4 = xv4[j + 16 * t];
                acc += w4.x * x4.x + w4.y * x4.y + w4.z * x4.z + w4.w * x4.w;
            }
            acc += __shfl_xor(acc, 1);
            acc += __shfl_xor(acc, 2);
            acc += __shfl_xor(acc, 4);
            acc += __shfl_xor(acc, 8);
            if (j == 0)
                s_x3[co3] = fmaxf(acc * sa3[co3] + ss3[co3], 0.f);
        }
    }
    __syncthreads();

    // ---- Phase 4: FC, coalesced over features, 4-way ci split ----
    {
        const int q = tid >> 8;       // 0..3
        const int f = tid & 255;
        float acc = 0.f;
        #pragma unroll
        for (int c = 0; c < 32; ++c) {
            int ci = q * 32 + c;
            acc += s_x3[ci] * wp[ci * 256 + f];
        }
        s_fc[q * 256 + f] = acc;
    }
    __syncthreads();
    if (tid < 256) {
        out[b * 256 + tid] = bp[tid] + s_fc[tid] + s_fc[256 + tid]
                           + s_fc[512 + tid] + s_fc[768 + tid];
    }
}

extern "C" void kernel_launch(void* const* d_in, const int* in_sizes, int n_in,
                              void* d_out, int out_size, void* d_ws, size_t ws_size,
                              hipStream_t stream) {
    const float* voxel = (const float*)d_in[0];
    const float* w1 = (const float*)d_in[1];
    const float* g1 = (const float*)d_in[2];
    const float* b1 = (const float*)d_in[3];
    const float* m1 = (const float*)d_in[4];
    const float* v1 = (const float*)d_in[5];
    const float* w2 = (const float*)d_in[6];
    const float* g2 = (const float*)d_in[7];
    const float* b2 = (const float*)d_in[8];
    const float* m2 = (const float*)d_in[9];
    const float* v2 = (const float*)d_in[10];
    const float* w3 = (const float*)d_in[11];
    const float* g3 = (const float*)d_in[12];
    const float* b3 = (const float*)d_in[13];
    const float* m3 = (const float*)d_in[14];
    const float* v3 = (const float*)d_in[15];
    const float* wp = (const float*)d_in[16];
    const float* bp = (const float*)d_in[17];
    float* out = (float*)d_out;

    backbone_fused_kernel<<<16, 1024, 0, stream>>>(
        voxel, w1, g1, b1, m1, v1, w2, g2, b2, m2, v2,
        w3, g3, b3, m3, v3, wp, bp, out);
}

// Round 6
// 21.533 us; speedup vs baseline: 9.7696x; 9.7696x over previous
//
#include <hip/hip_runtime.h>

#define BN_EPS 1e-5f

// Dependency cone of the single consumed output position (center voxel):
//   out(8,8,8) <- x2[15..17]^3 (64ch) <- x1[29..35]^3 (32ch) <- voxel[28..36]^3
// All interior; no padding logic.
//
// 2-kernel pipeline, every phase spread over 128 blocks:
//   K_A: (batch, 8-co-group): conv1 recomputed per block (cheap, saves a
//        launch) + conv2 for 8 co -> ws.x2[16][64][27]. grp0 seeds out=bias.
//   K_B: (batch, 16-co-group): conv3 center for 16 co (110 KB w3 slice) +
//        FC partial via device-scope atomicAdd (order-nondeterministic fp
//        rounding ~1e-6, far under threshold; K_A re-seeds bias every call
//        so graph replays are idempotent).
//
// R4/R5 lesson: 1024-thr blocks are pinned at 64 VGPRs (spill). 256-thr
// blocks compile at ~88-110 VGPRs (R2-verified). Peak live here ~80.

// ---------------- K_A: conv1 (all 32ch) + conv2 (8 co) ---------------------
__global__ __launch_bounds__(256) void convA_kernel(
    const float* __restrict__ voxel, const float* __restrict__ w1,
    const float* __restrict__ g1, const float* __restrict__ b1,
    const float* __restrict__ m1, const float* __restrict__ v1,
    const float* __restrict__ w2, const float* __restrict__ g2,
    const float* __restrict__ b2, const float* __restrict__ m2,
    const float* __restrict__ v2, const float* __restrict__ bp,
    float* __restrict__ x2out, float* __restrict__ out)
{
    const int b   = blockIdx.x >> 3;
    const int grp = blockIdx.x & 7;      // 8 conv2 output channels per block
    const int tid = threadIdx.x;

    __shared__ float s_in[729];                  // 9^3 input patch
    __shared__ float s_w1[864];                  // 32 x 27
    __shared__ __align__(16) float s_x1[10976];  // [343 pos][32 ci] channel-last
    __shared__ __align__(16) float s_w2[6912];   // [8 co][32 ci][27]
    __shared__ float sa1[32], ss1[32], sa2[8], ss2[8];

    if (grp == 0) out[b * 256 + tid] = bp[tid];  // bias seed for K_B atomics

    const float* vb = voxel + (size_t)b * 262144;
    for (int i = tid; i < 729; i += 256) {
        int z = i / 81, r = i % 81, y = r / 9, x = r % 9;
        s_in[i] = vb[(28 + z) * 4096 + (28 + y) * 64 + (28 + x)];
    }
    for (int i = tid; i < 864; i += 256) s_w1[i] = w1[i];
    {   // w2 slice for this group, coalesced float4
        const float4* src = (const float4*)(w2 + (size_t)grp * 8 * 32 * 27);
        float4* dst = (float4*)s_w2;
        for (int i = tid; i < 1728; i += 256) dst[i] = src[i];
    }
    if (tid < 32) {
        float a = g1[tid] * rsqrtf(v1[tid] + BN_EPS);
        sa1[tid] = a; ss1[tid] = b1[tid] - m1[tid] * a;
    } else if (tid < 40) {
        int c = grp * 8 + (tid - 32);
        float a = g2[c] * rsqrtf(v2[c] + BN_EPS);
        sa2[tid - 32] = a; ss2[tid - 32] = b2[c] - m2[c] * a;
    }
    __syncthreads();

    // ---- conv1 (stride 1) + BN + ReLU -> s_x1[pos][co] ----
    // Thread = (co = tid&31, row-group rg = tid>>5). Row task (z,y) computes
    // all 7 x-outputs from 9 input-row registers (27-tap reuse along x).
    // s_in reads: 2 distinct addrs/wave (2 rows x 32 co broadcast) - free.
    {
        const int co = tid & 31, rg = tid >> 5;
        float wc[27];
        #pragma unroll
        for (int k = 0; k < 27; ++k) wc[k] = s_w1[co * 27 + k];
        const float a = sa1[co], sh = ss1[co];
        for (int r = rg; r < 49; r += 8) {        // r = z*7 + y
            const int z = r / 7, y = r % 7;
            float acc[7];
            #pragma unroll
            for (int x = 0; x < 7; ++x) acc[x] = 0.f;
            #pragma unroll
            for (int kd = 0; kd < 3; ++kd)
            #pragma unroll
            for (int kh = 0; kh < 3; ++kh) {
                float row[9];
                #pragma unroll
                for (int x = 0; x < 9; ++x)
                    row[x] = s_in[(z + kd) * 81 + (y + kh) * 9 + x];
                #pragma unroll
                for (int kw = 0; kw < 3; ++kw) {
                    const float w = wc[kd * 9 + kh * 3 + kw];
                    #pragma unroll
                    for (int x = 0; x < 7; ++x)
                        acc[x] += row[x + kw] * w;
                }
            }
            #pragma unroll
            for (int x = 0; x < 7; ++x)           // banks 0..31 per x - clean
                s_x1[(r * 7 + x) * 32 + co] = fmaxf(acc[x] * a + sh, 0.f);
        }
    }
    __syncthreads();

    // ---- conv2 (stride 2) + BN + ReLU -> x2out[b][co][27] ----
    // Thread = (col = tid>>5 in 0..7, ci = tid&31). Weights LDS->regs:
    // lane stride 27 floats, gcd(27,32)=1 -> conflict-free; 2 co-groups/wave
    // broadcast. Activation rows: 7 b32 at pos*32+ci -> bank = ci, clean.
    {
        const int col = tid >> 5, ci = tid & 31;
        float wr[27];
        const float* wl = s_w2 + (col * 32 + ci) * 27;
        #pragma unroll
        for (int k = 0; k < 27; ++k) wr[k] = wl[k];
        float p[27];
        #pragma unroll
        for (int q = 0; q < 27; ++q) p[q] = 0.f;

        for (int z = 0; z < 7; ++z)
        for (int y = 0; y < 7; ++y) {             // uniform loops, no divergence
            float row[7];
            #pragma unroll
            for (int x = 0; x < 7; ++x)
                row[x] = s_x1[((z * 7 + y) * 7 + x) * 32 + ci];
            #pragma unroll
            for (int i = 0; i < 3; ++i) {
                const int kd = z - 2 * i;
                if (kd < 0 || kd > 2) continue;   // uniform branch (z uniform)
                #pragma unroll
                for (int jj = 0; jj < 3; ++jj) {
                    const int kh = y - 2 * jj;
                    if (kh < 0 || kh > 2) continue;
                    #pragma unroll
                    for (int k = 0; k < 3; ++k)
                    #pragma unroll
                    for (int kw = 0; kw < 3; ++kw)
                        p[i * 9 + jj * 3 + k] += row[2 * k + kw]
                                               * wr[kd * 9 + kh * 3 + kw];
                }
            }
        }

        #pragma unroll
        for (int q = 0; q < 27; ++q) {            // reduce over 32 ci lanes
            p[q] += __shfl_xor(p[q], 1);
            p[q] += __shfl_xor(p[q], 2);
            p[q] += __shfl_xor(p[q], 4);
            p[q] += __shfl_xor(p[q], 8);
            p[q] += __shfl_xor(p[q], 16);
        }
        float val = 0.f;
        #pragma unroll
        for (int q = 0; q < 27; ++q)              // compile-time indices only
            if (ci == q) val = p[q];
        if (ci < 27) {
            const int co = grp * 8 + col;
            x2out[((size_t)b * 64 + co) * 27 + ci] =
                fmaxf(val * sa2[col] + ss2[col], 0.f);
        }
    }
}

// ---------------- K_B: conv3 center (16 co) + FC partial --------------------
__global__ __launch_bounds__(256) void convB_kernel(
    const float* __restrict__ x2in, const float* __restrict__ w3,
    const float* __restrict__ g3, const float* __restrict__ b3,
    const float* __restrict__ m3, const float* __restrict__ v3,
    const float* __restrict__ wp, float* __restrict__ out)
{
    const int b   = blockIdx.x >> 3;
    const int grp = blockIdx.x & 7;      // 16 conv3 output channels per block
    const int tid = threadIdx.x;

    __shared__ __align__(16) float s_x2[1728];   // [64 ci][27]
    __shared__ float s_x3[16];

    const float4* src = (const float4*)(x2in + (size_t)b * 1728);
    float4* dst = (float4*)s_x2;
    for (int i = tid; i < 432; i += 256) dst[i] = src[i];
    __syncthreads();

    // conv3: 16-lane group per co; coalesced float4 over contiguous w3 row.
    {
        const int col = tid >> 4, j = tid & 15;
        const int co = grp * 16 + col;
        const float4* wv = (const float4*)(w3 + (size_t)co * 1728);
        const float4* xv = (const float4*)s_x2;
        float acc = 0.f;
        #pragma unroll
        for (int t = 0; t < 27; ++t) {
            float4 w4 = wv[j + 16 * t];
            float4 x4 = xv[j + 16 * t];
            acc += w4.x * x4.x + w4.y * x4.y + w4.z * x4.z + w4.w * x4.w;
        }
        acc += __shfl_xor(acc, 1);
        acc += __shfl_xor(acc, 2);
        acc += __shfl_xor(acc, 4);
        acc += __shfl_xor(acc, 8);
        if (j == 0) {
            float a = g3[co] * rsqrtf(v3[co] + BN_EPS);
            float s = b3[co] - m3[co] * a;
            s_x3[col] = fmaxf(acc * a + s, 0.f);
        }
    }
    __syncthreads();

    // FC partial over this group's 16 channels; wp reads coalesced (lane=f).
    float facc = 0.f;
    #pragma unroll
    for (int c = 0; c < 16; ++c)
        facc += s_x3[c] * wp[(grp * 16 + c) * 256 + tid];
    atomicAdd(&out[b * 256 + tid], facc);        // device-scope by default
}

extern "C" void kernel_launch(void* const* d_in, const int* in_sizes, int n_in,
                              void* d_out, int out_size, void* d_ws, size_t ws_size,
                              hipStream_t stream) {
    const float* voxel = (const float*)d_in[0];
    const float* w1 = (const float*)d_in[1];
    const float* g1 = (const float*)d_in[2];
    const float* b1 = (const float*)d_in[3];
    const float* m1 = (const float*)d_in[4];
    const float* v1 = (const float*)d_in[5];
    const float* w2 = (const float*)d_in[6];
    const float* g2 = (const float*)d_in[7];
    const float* b2 = (const float*)d_in[8];
    const float* m2 = (const float*)d_in[9];
    const float* v2 = (const float*)d_in[10];
    const float* w3 = (const float*)d_in[11];
    const float* g3 = (const float*)d_in[12];
    const float* b3 = (const float*)d_in[13];
    const float* m3 = (const float*)d_in[14];
    const float* v3 = (const float*)d_in[15];
    const float* wp = (const float*)d_in[16];
    const float* bp = (const float*)d_in[17];
    float* out = (float*)d_out;

    float* ws_x2 = (float*)d_ws;                 // [16][64][27] floats

    convA_kernel<<<128, 256, 0, stream>>>(
        voxel, w1, g1, b1, m1, v1, w2, g2, b2, m2, v2, bp, ws_x2, out);
    convB_kernel<<<128, 256, 0, stream>>>(
        ws_x2, w3, g3, b3, m3, v3, wp, out);
}